// Round 1
// 757.660 us; speedup vs baseline: 1.0095x; 1.0095x over previous
//
#include <hip/hip_runtime.h>
#include <math.h>

typedef _Float16 half8 __attribute__((ext_vector_type(8)));
typedef float floatx4 __attribute__((ext_vector_type(4)));

constexpr int CCH = 480, TT = 4, FY = 45, FX = 80;
constexpr int SN = 32, NROI = 512;
constexpr int KDIM = CCH * 49;      // 23520
constexpr int NDF_ = 1024, NC = 50;
constexpr float SCALE_X = 80.0f / 1280.0f;
constexpr float SCALE_Y = 45.0f / 720.0f;

constexpr int BM = 128, BN = 128, BK = 32;
constexpr int SK = 15;
constexpr int ITERS = (KDIM / BK) / SK;   // 49
static_assert(SK * ITERS * BK == KDIM, "split-K must tile K exactly");

// ---------------------------------------------------------------------------
// ROI-align, plane-staged: block = (channel-group of 5, batch).
// Planes staged to LDS with coalesced float4 loads (ideal 110.6 MB HBM read),
// bilinear gathers hit LDS instead of scattered global lines.
// Output: exact fp16 hi/lo split (x = hi + lo/2048), layout [r][c*49+pos].
// ---------------------------------------------------------------------------
constexpr int CG = 5;                      // channels per block
constexpr int PLANE = FY * FX;             // 3600 floats

__global__ __launch_bounds__(256) void roi_plane_kernel(
    const float* __restrict__ zvis,     // [16,480,4,45,80]
    const float* __restrict__ bboxs,    // [16,32,4]
    _Float16* __restrict__ phi,         // [512, 23520]
    _Float16* __restrict__ plo)         // [512, 23520]
{
    __shared__ float s_plane[CG * PLANE];   // 72 KB -> 2 blocks/CU

    const int cg  = blockIdx.x;             // 0..95
    const int b   = blockIdx.y;             // 0..15
    const int tid = threadIdx.x;
    const int c0  = cg * CG;

    // stage 5 planes (last time-slice) coalesced
    #pragma unroll
    for (int p = 0; p < CG; ++p) {
        const float* sp = zvis + (((size_t)(b * CCH + c0 + p)) * TT + (TT - 1)) * PLANE;
        float* dp = s_plane + p * PLANE;
        for (int i = tid; i < PLANE / 4; i += 256)
            *(float4*)(dp + i * 4) = *(const float4*)(sp + i * 4);
    }
    __syncthreads();

    // 32 rois x 49 positions = 1568 (r,pos) pairs; each pair -> CG channels
    for (int p = tid; p < SN * 49; p += 256) {
        const int r   = p / 49;
        const int pos = p - r * 49;

        const float4 bb = *(const float4*)(bboxs + ((size_t)(b * SN + r)) * 4);
        const float x1 = bb.x * SCALE_X - 0.5f;
        const float y1 = bb.y * SCALE_Y - 0.5f;
        const float x2 = bb.z * SCALE_X - 0.5f;
        const float y2 = bb.w * SCALE_Y - 0.5f;
        const float bw = (x2 - x1) / 7.0f;
        const float bh = (y2 - y1) / 7.0f;
        const int py = pos / 7, px = pos % 7;
        float y = y1 + ((float)py + 0.5f) * bh;
        float x = x1 + ((float)px + 0.5f) * bw;
        float v = ((y > -1.0f && y < (float)FY) && (x > -1.0f && x < (float)FX)) ? 1.0f : 0.0f;
        float yc = fminf(fmaxf(y, 0.0f), (float)(FY - 1));
        float xc = fminf(fmaxf(x, 0.0f), (float)(FX - 1));
        int yl = (int)floorf(yc);
        int xl = (int)floorf(xc);
        int yh = min(yl + 1, FY - 1);
        int xh = min(xl + 1, FX - 1);
        float ly = yc - (float)yl, lx = xc - (float)xl;
        float hy = 1.0f - ly, hx = 1.0f - lx;
        const int o0 = yl * FX + xl;
        const int o1 = yl * FX + xh;
        const int o2 = yh * FX + xl;
        const int o3 = yh * FX + xh;
        const float w0 = hy * hx * v;
        const float w1 = hy * lx * v;
        const float w2 = ly * hx * v;
        const float w3 = ly * lx * v;

        const size_t rbase = (size_t)(b * SN + r) * KDIM + pos;
        #pragma unroll
        for (int c = 0; c < CG; ++c) {
            const float* f = s_plane + c * PLANE;
            float val = f[o0] * w0 + f[o1] * w1 + f[o2] * w2 + f[o3] * w3;
            _Float16 hi = (_Float16)val;
            _Float16 lo = (_Float16)((val - (float)hi) * 2048.0f);
            size_t oidx = rbase + (size_t)(c0 + c) * 49;
            phi[oidx] = hi;
            plo[oidx] = lo;
        }
    }
}

// ---------------------------------------------------------------------------
// Z bias init: Z[m][n] = b_vis[n] + norms[m]*w_spc[n] + b_spc[n]
// ---------------------------------------------------------------------------
__global__ __launch_bounds__(256) void bias_init_kernel(
    const float* __restrict__ b_vis, const float* __restrict__ norms,
    const float* __restrict__ w_spc, const float* __restrict__ b_spc,
    float* __restrict__ Z)
{
    const int m = blockIdx.x;
    const int n = threadIdx.x * 4;
    const float nm = norms[m];
    float4 bv = *(const float4*)(b_vis + n);
    float4 ws = *(const float4*)(w_spc + n);
    float4 bs = *(const float4*)(b_spc + n);
    float4 o;
    o.x = bv.x + nm * ws.x + bs.x;
    o.y = bv.y + nm * ws.y + bs.y;
    o.z = bv.z + nm * ws.z + bs.z;
    o.w = bv.w + nm * ws.w + bs.w;
    *(float4*)(Z + (size_t)m * NDF_ + n) = o;
}

// ---------------------------------------------------------------------------
// Split-K MFMA GEMM, 3-term fp16 error compensation (~fp32 accuracy).
// Z += A @ W^T, A[512][23520] (fp16 hi/lo), W[1024][23520] fp32 (split inline).
// XCD-chunked block remap: 480 blocks = 8 XCDs x 60; each XCD owns a
// contiguous (kz,m,n) range so A-slices AND W-slices are consumed within
// one XCD's L2 (default linearization re-fetched A from HBM ~8x).
// ---------------------------------------------------------------------------
__device__ __forceinline__ void async_cp16(const void* g, void* l) {
    __builtin_amdgcn_global_load_lds(
        (const __attribute__((address_space(1))) void*)g,
        (__attribute__((address_space(3))) void*)l, 16, 0, 0);
}

__global__ __launch_bounds__(256, 2) void gemm3_kernel(
    const _Float16* __restrict__ Ahi, const _Float16* __restrict__ Alo,
    const float* __restrict__ W, float* __restrict__ Z)
{
    __shared__ __align__(16) _Float16 sAh[BM * BK];
    __shared__ __align__(16) _Float16 sAl[BM * BK];
    __shared__ __align__(16) _Float16 sBh[BN * BK];
    __shared__ __align__(16) _Float16 sBl[BN * BK];

    const int tid  = threadIdx.x;
    const int wave = tid >> 6;
    const int lane = tid & 63;

    // bijective XCD-chunk remap (480 % 8 == 0): hw dispatch id -> logical id
    const int flat = blockIdx.x + ((blockIdx.y + (blockIdx.z << 2)) << 3);
    const int id2  = (flat & 7) * 60 + (flat >> 3);
    const int n0 = (id2 & 7) * BN;
    const int m0 = ((id2 >> 3) & 3) * BM;
    const int kz = id2 >> 5;

    floatx4 ach[4][4], acm[4][4];
    #pragma unroll
    for (int i = 0; i < 4; ++i)
        #pragma unroll
        for (int j = 0; j < 4; ++j) {
            ach[i][j] = (floatx4){0.f, 0.f, 0.f, 0.f};
            acm[i][j] = (floatx4){0.f, 0.f, 0.f, 0.f};
        }

    // A staging map: chunk = 16 rows x 32 elems (1 KB); lane -> row l>>2, col (l&3)*8
    const int chunk = wave * 2;
    const int arow0 = chunk * 16 + (lane >> 2);
    const int acol  = (lane & 3) * 8;

    // B staging map: 2 threads per row, 16 fp32 each
    const int brow = tid >> 1;
    const int bkc  = (tid & 1) * 16;

    // wave tile: 2x2 waves of 64x64
    const int wr = (wave >> 1) * 64;
    const int wc = (wave & 1) * 64;
    const int frow = lane & 15;
    const int ko   = (lane >> 4) * 8;

    for (int it = 0; it < ITERS; ++it) {
        const int k0 = (kz * ITERS + it) * BK;

        // async A hi/lo -> LDS (2 chunks per wave per buffer)
        #pragma unroll
        for (int i = 0; i < 2; ++i) {
            const size_t go = (size_t)(m0 + arow0 + i * 16) * KDIM + k0 + acol;
            async_cp16(Ahi + go, (void*)(sAh + (chunk + i) * 512));
            async_cp16(Alo + go, (void*)(sAl + (chunk + i) * 512));
        }

        // B: 16 fp32 -> fp16 hi/lo
        const float* gW = W + (size_t)(n0 + brow) * KDIM + k0 + bkc;
        float xs[16];
        *(float4*)(xs + 0)  = *(const float4*)(gW + 0);
        *(float4*)(xs + 4)  = *(const float4*)(gW + 4);
        *(float4*)(xs + 8)  = *(const float4*)(gW + 8);
        *(float4*)(xs + 12) = *(const float4*)(gW + 12);
        _Float16 hs[16], ls[16];
        #pragma unroll
        for (int e = 0; e < 16; ++e) {
            _Float16 h = (_Float16)xs[e];
            hs[e] = h;
            ls[e] = (_Float16)((xs[e] - (float)h) * 2048.0f);
        }
        *(half8*)(sBh + brow * 32 + bkc)     = *(half8*)(hs);
        *(half8*)(sBh + brow * 32 + bkc + 8) = *(half8*)(hs + 8);
        *(half8*)(sBl + brow * 32 + bkc)     = *(half8*)(ls);
        *(half8*)(sBl + brow * 32 + bkc + 8) = *(half8*)(ls + 8);

        __syncthreads();

        half8 bh[4], bl[4];
        #pragma unroll
        for (int ni = 0; ni < 4; ++ni) {
            const int n_l = wc + ni * 16 + frow;
            bh[ni] = *(const half8*)(sBh + n_l * 32 + ko);
            bl[ni] = *(const half8*)(sBl + n_l * 32 + ko);
        }
        #pragma unroll
        for (int mi = 0; mi < 4; ++mi) {
            const int m_l = wr + mi * 16 + frow;
            half8 ah = *(const half8*)(sAh + m_l * 32 + ko);
            half8 al = *(const half8*)(sAl + m_l * 32 + ko);
            #pragma unroll
            for (int ni = 0; ni < 4; ++ni) {
                ach[mi][ni] = __builtin_amdgcn_mfma_f32_16x16x32_f16(ah, bh[ni], ach[mi][ni], 0, 0, 0);
                acm[mi][ni] = __builtin_amdgcn_mfma_f32_16x16x32_f16(ah, bl[ni], acm[mi][ni], 0, 0, 0);
                acm[mi][ni] = __builtin_amdgcn_mfma_f32_16x16x32_f16(al, bh[ni], acm[mi][ni], 0, 0, 0);
            }
        }
        __syncthreads();
    }

    // epilogue: C/D layout col=lane&15 (n), row=(lane>>4)*4+reg (m)
    const float inv2048 = 1.0f / 2048.0f;
    #pragma unroll
    for (int mi = 0; mi < 4; ++mi)
        #pragma unroll
        for (int ni = 0; ni < 4; ++ni)
            #pragma unroll
            for (int rr = 0; rr < 4; ++rr) {
                int gm = m0 + wr + mi * 16 + (lane >> 4) * 4 + rr;
                int gn = n0 + wc + ni * 16 + (lane & 15);
                unsafeAtomicAdd(&Z[(size_t)gm * NDF_ + gn],
                                ach[mi][ni][rr] + acm[mi][ni][rr] * inv2048);
            }
}

// ---------------------------------------------------------------------------
// Clustering: dist to 50 centroids, s=(1+dist)^-1 normalized, argmax.
// Tail (normalize + argmax + S write) wave-parallel instead of tid==0 serial.
// ---------------------------------------------------------------------------
__global__ __launch_bounds__(256) void cluster_kernel(
    const float* __restrict__ Z, const float* __restrict__ cent,
    float* __restrict__ S, float* __restrict__ Cc)
{
    const int r = blockIdx.x;
    const int tid = threadIdx.x;
    __shared__ float sz[NDF_];
    __shared__ float sd[NC];

    for (int d = tid; d < NDF_; d += 256) sz[d] = Z[(size_t)r * NDF_ + d];
    __syncthreads();

    const int wave = tid >> 6;
    const int lane = tid & 63;
    for (int k = wave; k < NC; k += 4) {
        float sum = 0.0f;
        const float* ck = cent + (size_t)k * NDF_;
        for (int d = lane; d < NDF_; d += 64) {
            float df = sz[d] - ck[d];
            sum += df * df;
        }
        #pragma unroll
        for (int off = 32; off > 0; off >>= 1) sum += __shfl_down(sum, off, 64);
        if (lane == 0) sd[k] = 1.0f / (1.0f + sqrtf(sum));
    }
    __syncthreads();

    if (tid < 64) {
        const int k = tid;
        const float v = (k < NC) ? sd[k] : 0.0f;
        // total (valid in lane 0), then broadcast
        float tot = v;
        #pragma unroll
        for (int off = 32; off > 0; off >>= 1) tot += __shfl_down(tot, off, 64);
        const float inv = 1.0f / __shfl(tot, 0, 64);
        const float sv = v * inv;
        if (k < NC) S[(size_t)r * NC + k] = sv;
        // argmax, ties -> smallest index (matches serial first-max scan)
        float bv = (k < NC) ? sv : -1.0f;
        int bk = k;
        #pragma unroll
        for (int off = 32; off > 0; off >>= 1) {
            float ov = __shfl_down(bv, off, 64);
            int oi = __shfl_down(bk, off, 64);
            if (ov > bv || (ov == bv && oi < bk)) { bv = ov; bk = oi; }
        }
        if (tid == 0) Cc[r] = (float)bk;
    }
}

// ---------------------------------------------------------------------------
extern "C" void kernel_launch(void* const* d_in, const int* in_sizes, int n_in,
                              void* d_out, int out_size, void* d_ws, size_t ws_size,
                              hipStream_t stream)
{
    const float* z_vis     = (const float*)d_in[0];
    const float* bboxs     = (const float*)d_in[1];
    const float* norms     = (const float*)d_in[2];
    const float* w_vis     = (const float*)d_in[3];
    const float* b_vis     = (const float*)d_in[4];
    const float* w_spc     = (const float*)d_in[5];
    const float* b_spc     = (const float*)d_in[6];
    const float* centroids = (const float*)d_in[7];

    _Float16* phi = (_Float16*)d_ws;                      // 24.1 MB
    _Float16* plo = phi + (size_t)NROI * KDIM;            // 24.1 MB (total 48.2)

    float* z_out = (float*)d_out;                         // [512,1024]
    float* s_out = z_out + (size_t)NROI * NDF_;           // [512,50]
    float* c_out = s_out + (size_t)NROI * NC;             // [512]

    dim3 rgrid(CCH / CG, 16);                             // 96 x 16 blocks
    roi_plane_kernel<<<rgrid, 256, 0, stream>>>(z_vis, bboxs, phi, plo);

    bias_init_kernel<<<NROI, 256, 0, stream>>>(b_vis, norms, w_spc, b_spc, z_out);

    dim3 ggrid(NDF_ / BN, NROI / BM, SK);
    gemm3_kernel<<<ggrid, 256, 0, stream>>>(phi, plo, w_vis, z_out);

    cluster_kernel<<<NROI, 256, 0, stream>>>(z_out, centroids, s_out, c_out);
}